// Round 16
// baseline (622.125 us; speedup 1.0000x reference)
//
#include <hip/hip_runtime.h>
#include <math.h>

#define D 64
#define NB 1024      // sort buckets per relation
#define CHUNKE 4096  // edges per partition workgroup

typedef __attribute__((ext_vector_type(8))) short s8bf;   // 8 x bf16 (4 VGPR) MFMA A/B frag
typedef __attribute__((ext_vector_type(4))) float fx4;    // 4 x f32 MFMA C/D frag
typedef __attribute__((ext_vector_type(4))) int ix4;      // native int4

__device__ __forceinline__ float bf2f(unsigned short u) {
    union { unsigned int i; float f; } v; v.i = ((unsigned int)u) << 16; return v.f;
}
__device__ __forceinline__ unsigned short f2bf(float f) {
    union { float f; unsigned int i; } v; v.f = f;
    unsigned int r = v.i + 0x7FFFu + ((v.i >> 16) & 1u);
    return (unsigned short)(r >> 16);
}
// hardware packed bf16 atomic add (gfx942+/gfx950); inline asm avoids header dependence
__device__ __forceinline__ void atomAddPkBf16(unsigned short* addr, float a, float b) {
    unsigned int pk = ((unsigned int)f2bf(b) << 16) | (unsigned int)f2bf(a);
    asm volatile("global_atomic_pk_add_bf16 %0, %1, off" :: "v"(addr), "v"(pk) : "memory");
}

// ============================ initial gather (both tables -> bf16, one launch) ====================
__global__ __launch_bounds__(256) void k_gather2(const float* __restrict__ ue,
                                                 const float* __restrict__ ie,
                                                 const int* __restrict__ uid,
                                                 const int* __restrict__ iid,
                                                 unsigned short* __restrict__ uh0,
                                                 unsigned short* __restrict__ ih0, int NU, int NI) {
    int i = blockIdx.x * blockDim.x + threadIdx.x;
    if (i >= (NU + NI) * D) return;
    int r = i >> 6, c = i & 63;
    if (r < NU) uh0[(size_t)r * D + c] = f2bf(ue[(size_t)uid[r] * D + c]);
    else { int j = r - NU; ih0[(size_t)j * D + c] = f2bf(ie[(size_t)iid[j] * D + c]); }
}

// ============================ weight transpose+bf16 prep (once) ============================
__global__ __launch_bounds__(256) void k_wprep(const float* __restrict__ Wu,
                                               const float* __restrict__ Wi,
                                               const float* __restrict__ Wuu,
                                               const float* __restrict__ Wii,
                                               unsigned short* __restrict__ WuT,
                                               unsigned short* __restrict__ WiT,
                                               unsigned short* __restrict__ WuuT,
                                               unsigned short* __restrict__ WiiT, int L) {
    int i = blockIdx.x * blockDim.x + threadIdx.x;
    int n1 = L * 64 * 64, n2 = L * 64 * 128;
    if (i < n1) {
        int l = i >> 12, c = (i >> 6) & 63, k = i & 63;
        WuT[i] = f2bf(Wu[l * 4096 + k * 64 + c]);
        WiT[i] = f2bf(Wi[l * 4096 + k * 64 + c]);
    }
    if (i < n2) {
        int l = i >> 13, c = (i >> 7) & 63, k = i & 127;
        WuuT[i] = f2bf(Wuu[l * 8192 + k * 64 + c]);
        WiiT[i] = f2bf(Wii[l * 8192 + k * 64 + c]);
    }
}

// ============================ node-level CSR scan kernels ============================
__global__ __launch_bounds__(256) void k_scan_block2(const int* __restrict__ cu, int* __restrict__ rp_u,
                                                     const int* __restrict__ ci, int* __restrict__ rp_i,
                                                     int* __restrict__ bsums, int nbU, int NU, int NI) {
    __shared__ int ts[256];
    bool rel = blockIdx.x >= (unsigned)nbU;
    const int* in = rel ? ci : cu;
    int* out = rel ? rp_i : rp_u;
    int n = rel ? NI : NU;
    int boff = rel ? blockIdx.x - nbU : blockIdx.x;
    int t = threadIdx.x;
    int base = boff * 2048 + t * 8;
    int v[8]; int s = 0;
#pragma unroll
    for (int k = 0; k < 8; ++k) { int idx = base + k; v[k] = idx < n ? in[idx] : 0; s += v[k]; }
    ts[t] = s; __syncthreads();
    for (int off = 1; off < 256; off <<= 1) {
        int x = (t >= off) ? ts[t - off] : 0;
        __syncthreads(); ts[t] += x; __syncthreads();
    }
    int excl = ts[t] - s;
    if (t == 255) bsums[blockIdx.x] = ts[255];
    int run = excl;
#pragma unroll
    for (int k = 0; k < 8; ++k) { int idx = base + k; if (idx < n) out[idx] = run; run += v[k]; }
}

__global__ __launch_bounds__(256) void k_scan_small(int* __restrict__ bsums, int nbU, int nbI) {
    __shared__ int ts[256];
    int t = threadIdx.x;
    int half = t >> 7, local = t & 127;
    int nb = half ? nbI : nbU;
    int g = half ? nbU + local : local;
    int v = local < nb ? bsums[g] : 0;
    ts[t] = v; __syncthreads();
    for (int off = 1; off < 128; off <<= 1) {
        int x = (local >= off) ? ts[t - off] : 0;
        __syncthreads(); ts[t] += x; __syncthreads();
    }
    if (local < nb) bsums[g] = ts[t] - v;
}

__global__ __launch_bounds__(256) void k_fixup2(int* __restrict__ rp_u, int* __restrict__ rp_i,
                                                const int* __restrict__ bsums,
                                                int* __restrict__ cu, int* __restrict__ ci,
                                                int NU, int NI, int E, int nbU) {
    int i = blockIdx.x * blockDim.x + threadIdx.x;
    if (i < NU) {
        int v = rp_u[i] + bsums[i >> 11]; rp_u[i] = v; cu[i] = v;
        if (i == 0) rp_u[NU] = E;
    } else if (i < NU + NI) {
        int j = i - NU;
        int v = rp_i[j] + bsums[nbU + (j >> 11)]; rp_i[j] = v; ci[j] = v;
        if (j == 0) rp_i[NI] = E;
    }
}

// ============================ radix partition pass 1: bucket hist + node hist (fused) ============
__global__ __launch_bounds__(256) void k_phist(const int* __restrict__ bd,
                                               const int* __restrict__ pd,
                                               int* __restrict__ H,
                                               int* __restrict__ cu, int* __restrict__ ci,
                                               int E, int nwgE,
                                               unsigned npbU, unsigned npbI) {
    bool rel = blockIdx.x >= (unsigned)nwgE;
    int wg = rel ? blockIdx.x - nwgE : blockIdx.x;
    const int* dsts = rel ? pd : bd;
    unsigned npb = rel ? npbI : npbU;
    int* Hr = H + (rel ? NB * nwgE : 0);
    int* nodecnt = rel ? ci : cu;
    __shared__ int hist[NB];
    int t = threadIdx.x;
    for (int j = t; j < NB; j += 256) hist[j] = 0;
    __syncthreads();
    int base = wg * CHUNKE;
#pragma unroll
    for (int k = 0; k < CHUNKE / 256; ++k) {
        int e = base + t + k * 256;
        if (e < E) {
            int d = dsts[e];
            atomicAdd(&hist[(unsigned)d / npb], 1);
            atomicAdd(&nodecnt[d], 1);
        }
    }
    __syncthreads();
    for (int j = t; j < NB; j += 256) Hr[j * nwgE + wg] = hist[j];
}

// generic exclusive scan (3 kernels) over H
__global__ __launch_bounds__(256) void k_gscan_block(const int* __restrict__ in,
                                                     int* __restrict__ out,
                                                     int* __restrict__ bsums, int n) {
    __shared__ int ts[256];
    int t = threadIdx.x;
    int base = blockIdx.x * 2048 + t * 8;
    int v[8]; int s = 0;
#pragma unroll
    for (int k = 0; k < 8; ++k) { int idx = base + k; v[k] = idx < n ? in[idx] : 0; s += v[k]; }
    ts[t] = s; __syncthreads();
    for (int off = 1; off < 256; off <<= 1) {
        int x = (t >= off) ? ts[t - off] : 0;
        __syncthreads(); ts[t] += x; __syncthreads();
    }
    int excl = ts[t] - s;
    if (t == 255) bsums[blockIdx.x] = ts[255];
    int run = excl;
#pragma unroll
    for (int k = 0; k < 8; ++k) { int idx = base + k; if (idx < n) out[idx] = run; run += v[k]; }
}

__global__ __launch_bounds__(256) void k_gscan_small(int* __restrict__ bsums, int nb) {
    __shared__ int ts[256];
    int t = threadIdx.x;
    int v = t < nb ? bsums[t] : 0;
    ts[t] = v; __syncthreads();
    for (int off = 1; off < 256; off <<= 1) {
        int x = (t >= off) ? ts[t - off] : 0;
        __syncthreads(); ts[t] += x; __syncthreads();
    }
    if (t < nb) bsums[t] = ts[t] - v;
}

__global__ __launch_bounds__(256) void k_gscan_fix(int* __restrict__ out,
                                                   const int* __restrict__ bsums, int n) {
    int i = blockIdx.x * blockDim.x + threadIdx.x;
    if (i < n) out[i] += bsums[i >> 11];
}

// ============================ radix partition pass 2: place via LDS cursors ======================
__global__ __launch_bounds__(256) void k_ppart(
    const int* __restrict__ bs, const int* __restrict__ bd, const float* __restrict__ bt,
    const int* __restrict__ ps, const int* __restrict__ pd, const float* __restrict__ pt,
    const int* __restrict__ H, ix4* __restrict__ stg_by, ix4* __restrict__ stg_pby,
    int E, int nwgE, unsigned npbU, unsigned npbI) {
    bool rel = blockIdx.x >= (unsigned)nwgE;
    int wg = rel ? blockIdx.x - nwgE : blockIdx.x;
    const int* srcs = rel ? ps : bs;
    const int* dsts = rel ? pd : bd;
    const float* tms = rel ? pt : bt;
    unsigned npb = rel ? npbI : npbU;
    const int* Hr = H + (rel ? NB * nwgE : 0);
    ix4* stg = rel ? stg_pby : stg_by;
    int sub = rel ? E : 0;
    __shared__ int cur[NB];
    int t = threadIdx.x;
    for (int j = t; j < NB; j += 256) cur[j] = Hr[j * nwgE + wg] - sub;
    __syncthreads();
    int base = wg * CHUNKE;
#pragma unroll
    for (int k = 0; k < CHUNKE / 256; ++k) {
        int e = base + t + k * 256;
        if (e < E) {
            int d = dsts[e];
            int pos = atomicAdd(&cur[(unsigned)d / npb], 1);
            ix4 v = {srcs[e], __float_as_int(tms[e]), d, 0};
            stg[pos] = v;
        }
    }
}

// pass 3: one WG per bucket; exact per-node placement (bucket window L2-resident)
__global__ __launch_bounds__(256) void k_sortfin(
    const ix4* __restrict__ stg_by, const ix4* __restrict__ stg_pby,
    const int* __restrict__ rp_u, const int* __restrict__ rp_i,
    int* __restrict__ cu, int* __restrict__ ci,
    ix4* __restrict__ by_e, ix4* __restrict__ pby_e,
    int NU, int NI, int npbU, int npbI) {
    bool rel = blockIdx.x >= (unsigned)NB;
    int b = rel ? blockIdx.x - NB : blockIdx.x;
    const ix4* stg = rel ? stg_pby : stg_by;
    const int* rp = rel ? rp_i : rp_u;
    int* cur = rel ? ci : cu;
    ix4* out = rel ? pby_e : by_e;
    int n = rel ? NI : NU;
    int npb = rel ? npbI : npbU;
    long long s0 = (long long)b * npb; if (s0 > n) s0 = n;
    long long s1 = (long long)(b + 1) * npb; if (s1 > n) s1 = n;
    int beg = rp[s0], end = rp[s1];
    for (int j = beg + threadIdx.x; j < end; j += 256) {
        ix4 q = stg[j];
        int pos = atomicAdd(&cur[q.z], 1);
        out[pos] = q;
    }
}

// ============================ transform: MFMA 16x16x32 bf16 (h is bf16) ==========================
__global__ __launch_bounds__(256) void k_transform4(
    const unsigned short* __restrict__ user_h, const unsigned short* __restrict__ item_h,
    const unsigned short* __restrict__ WuT_l, const unsigned short* __restrict__ WiT_l,
    unsigned short* __restrict__ uh, unsigned short* __restrict__ ih,
    int NU, int NI, int G) {
    bool rel = blockIdx.x >= (unsigned)G;
    int b = rel ? blockIdx.x - G : blockIdx.x;
    const unsigned short* in = rel ? item_h : user_h;
    const unsigned short* WT = rel ? WiT_l : WuT_l;
    unsigned short* out = rel ? ih : uh;
    int n = rel ? NI : NU;
    int lane = threadIdx.x & 63;
    int l15 = lane & 15, l4 = lane >> 4;
    s8bf bfr[8];
#pragma unroll
    for (int ct = 0; ct < 4; ++ct)
#pragma unroll
        for (int kk = 0; kk < 2; ++kk)
            bfr[ct * 2 + kk] = *(const s8bf*)&WT[(ct * 16 + l15) * 64 + kk * 32 + l4 * 8];
    int wave = b * 4 + (threadIdx.x >> 6);
    int nw = G * 4;
    int ntiles = (n + 15) >> 4;
    for (int t = wave; t < ntiles; t += nw) {
        int r = t * 16 + l15; if (r >= n) r = n - 1;
        s8bf afr0 = *(const s8bf*)&in[(size_t)r * 64 + l4 * 8];
        s8bf afr1 = *(const s8bf*)&in[(size_t)r * 64 + 32 + l4 * 8];
#pragma unroll
        for (int ct = 0; ct < 4; ++ct) {
            fx4 c = {0.f, 0.f, 0.f, 0.f};
            c = __builtin_amdgcn_mfma_f32_16x16x32_bf16(afr0, bfr[ct * 2 + 0], c, 0, 0, 0);
            c = __builtin_amdgcn_mfma_f32_16x16x32_bf16(afr1, bfr[ct * 2 + 1], c, 0, 0, 0);
#pragma unroll
            for (int i2 = 0; i2 < 4; ++i2) {
                int row = t * 16 + l4 * 4 + i2;
                if (row < n) out[(size_t)row * 64 + ct * 16 + l15] = f2bf(c[i2]);
            }
        }
    }
}

// ============================ edge kernel: 16-lane groups, revolutions-cos, bf16 pk-atomic agg ====
// VALU cuts vs round-15: freq/phase pre-scaled to revolutions once per block -> raw v_cos
// (no per-cos scale mul / libm range reduction; args bounded: t in [0,1], f <= 1 rad -> <0.16 rev);
// dot terms (c+s) reused for the accumulation when key-encode == e-encode (saves 4 adds/edge).
__global__ __launch_bounds__(256) void k_edge2(
    const unsigned short* __restrict__ ihF, const unsigned short* __restrict__ uhF,
    const ix4* __restrict__ by_e, const ix4* __restrict__ pby_e,
    const float* __restrict__ uf, const float* __restrict__ up,
    const float* __restrict__ ukf, const float* __restrict__ ukp,
    const float* __restrict__ ifq, const float* __restrict__ ipq,
    const float* __restrict__ ikf, const float* __restrict__ ikp,
    unsigned short* __restrict__ agg_u, float* __restrict__ den_u,
    unsigned short* __restrict__ agg_i, float* __restrict__ den_i,
    int E, int EB) {
    bool rel = blockIdx.x >= (unsigned)EB;  // false: 'by' item->user, true: 'pby' user->item
    int rblk = rel ? blockIdx.x - EB : blockIdx.x;
    const unsigned short* srcF = rel ? uhF : ihF;
    const unsigned short* dstF = rel ? ihF : uhF;
    const ix4* ee = rel ? pby_e : by_e;
    const float* efq = rel ? ifq : uf;
    const float* eps = rel ? ipq : up;
    const float* kfq = rel ? ikf : ukf;
    const float* kps = rel ? ikp : ukp;
    unsigned short* agg = rel ? agg_i : agg_u;
    float* den = rel ? den_i : den_u;

    int lane = threadIdx.x & 15;
    int grp  = threadIdx.x >> 4;
    int base = rblk * 256 + grp * 16;
    if (base >= E) return;
    float2 ef01 = ((const float2*)efq)[lane];        // dims 2l, 2l+1
    float2 ef23 = ((const float2*)efq)[lane + 16];   // dims 32+2l, 32+2l+1
    float2 ep01 = ((const float2*)eps)[lane];
    float2 ep23 = ((const float2*)eps)[lane + 16];
    float2 kf01 = ((const float2*)kfq)[lane];
    float2 kf23 = ((const float2*)kfq)[lane + 16];
    float2 kp01 = ((const float2*)kps)[lane];
    float2 kp23 = ((const float2*)kps)[lane + 16];
    bool same = ef01.x == kf01.x && ef01.y == kf01.y && ef23.x == kf23.x && ef23.y == kf23.y &&
                ep01.x == kp01.x && ep01.y == kp01.y && ep23.x == kp23.x && ep23.y == kp23.y;
    same = __all(same);  // uniform: key time-encode identical to e time-encode (raw compare)
    // scale to revolutions for raw v_cos
    const float R = 0.15915494309189535f;
    ef01.x *= R; ef01.y *= R; ef23.x *= R; ef23.y *= R;
    ep01.x *= R; ep01.y *= R; ep23.x *= R; ep23.y *= R;
    kf01.x *= R; kf01.y *= R; kf23.x *= R; kf23.y *= R;
    kp01.x *= R; kp01.y *= R; kp23.x *= R; kp23.y *= R;

    float a0 = 0, a1 = 0, a2 = 0, a3 = 0, dn = 0;
    float d0 = 0, d1 = 0, d2 = 0, d3 = 0;
    int cur = -1;
    for (int j = 0; j < 16; ++j) {
        int e = base + j;
        if (e >= E) break;
        ix4 q = ee[e];                          // broadcast 16B
        int s = q.x; float t = __int_as_float(q.y); int dd = q.z;
        if (dd != cur) {  // group-uniform
            if (cur >= 0) {
                unsigned short* ap = &agg[(size_t)cur * D + 2 * lane];
                atomAddPkBf16(ap, a0, a1);
                atomAddPkBf16(ap + 32, a2, a3);
                if (lane == 0) unsafeAtomicAdd(&den[cur], dn);
            }
            a0 = a1 = a2 = a3 = 0; dn = 0; cur = dd;
            unsigned int u0 = *(const unsigned int*)&dstF[(size_t)dd * D + 2 * lane];
            unsigned int u1 = *(const unsigned int*)&dstF[(size_t)dd * D + 32 + 2 * lane];
            d0 = bf2f((unsigned short)u0); d1 = bf2f((unsigned short)(u0 >> 16));
            d2 = bf2f((unsigned short)u1); d3 = bf2f((unsigned short)(u1 >> 16));
        }
        unsigned int s01 = *(const unsigned int*)&srcF[(size_t)s * D + 2 * lane];
        unsigned int s23 = *(const unsigned int*)&srcF[(size_t)s * D + 32 + 2 * lane];
        float s0 = bf2f((unsigned short)s01), s1 = bf2f((unsigned short)(s01 >> 16));
        float s2 = bf2f((unsigned short)s23), s3 = bf2f((unsigned short)(s23 >> 16));
        float c0 = __builtin_amdgcn_cosf(fmaf(t, ef01.x, ep01.x));
        float c1 = __builtin_amdgcn_cosf(fmaf(t, ef01.y, ep01.y));
        float c2 = __builtin_amdgcn_cosf(fmaf(t, ef23.x, ep23.x));
        float c3 = __builtin_amdgcn_cosf(fmaf(t, ef23.y, ep23.y));
        float t0 = c0 + s0, t1 = c1 + s1, t2 = c2 + s2, t3 = c3 + s3;
        float p = t0 * d0 + t1 * d1 + t2 * d2 + t3 * d3;
        p += __shfl_xor(p, 1); p += __shfl_xor(p, 2);
        p += __shfl_xor(p, 4); p += __shfl_xor(p, 8);
        float ex = __expf(p * 0.125f);
        if (same) {  // s + k == s + c == t (dot terms reused)
            a0 = fmaf(ex, t0, a0); a1 = fmaf(ex, t1, a1);
            a2 = fmaf(ex, t2, a2); a3 = fmaf(ex, t3, a3);
        } else {
            float k0 = __builtin_amdgcn_cosf(fmaf(t, kf01.x, kp01.x));
            float k1 = __builtin_amdgcn_cosf(fmaf(t, kf01.y, kp01.y));
            float k2 = __builtin_amdgcn_cosf(fmaf(t, kf23.x, kp23.x));
            float k3 = __builtin_amdgcn_cosf(fmaf(t, kf23.y, kp23.y));
            a0 = fmaf(ex, s0 + k0, a0); a1 = fmaf(ex, s1 + k1, a1);
            a2 = fmaf(ex, s2 + k2, a2); a3 = fmaf(ex, s3 + k3, a3);
        }
        dn += ex;
    }
    if (cur >= 0) {
        unsigned short* ap = &agg[(size_t)cur * D + 2 * lane];
        atomAddPkBf16(ap, a0, a1);
        atomAddPkBf16(ap + 32, a2, a3);
        if (lane == 0) unsafeAtomicAdd(&den[cur], dn);
    }
}

// ============================ update: MFMA 16x16x32 bf16, K=128, in-place ELU (agg+h bf16) =======
__global__ __launch_bounds__(256) void k_update4(
    unsigned short* __restrict__ user_h, unsigned short* __restrict__ item_h,
    const unsigned short* __restrict__ agg_u, const float* __restrict__ den_u,
    const unsigned short* __restrict__ agg_i, const float* __restrict__ den_i,
    const unsigned short* __restrict__ WuuT_l, const unsigned short* __restrict__ WiiT_l,
    int NU, int NI, int G) {
    bool rel = blockIdx.x >= (unsigned)G;
    int b = rel ? blockIdx.x - G : blockIdx.x;
    unsigned short* h = rel ? item_h : user_h;
    const unsigned short* agg = rel ? agg_i : agg_u;
    const float* den = rel ? den_i : den_u;
    const unsigned short* WT = rel ? WiiT_l : WuuT_l;
    int n = rel ? NI : NU;
    int lane = threadIdx.x & 63;
    int l15 = lane & 15, l4 = lane >> 4;
    s8bf bfr[16];
#pragma unroll
    for (int ct = 0; ct < 4; ++ct)
#pragma unroll
        for (int kk = 0; kk < 4; ++kk)
            bfr[ct * 4 + kk] = *(const s8bf*)&WT[(ct * 16 + l15) * 128 + kk * 32 + l4 * 8];
    int wave = b * 4 + (threadIdx.x >> 6);
    int nw = G * 4;
    int ntiles = (n + 15) >> 4;
    for (int t = wave; t < ntiles; t += nw) {
        int r = t * 16 + l15; if (r >= n) r = n - 1;
        float dd = den[r];
        float inv = dd > 0.f ? 1.f / dd : 0.f;   // empty segment -> agg contribution 0
        s8bf afr[4];
#pragma unroll
        for (int kk = 0; kk < 2; ++kk) {         // agg half (bf16), scale by inv
            s8bf a = *(const s8bf*)&agg[(size_t)r * 64 + kk * 32 + l4 * 8];
            s8bf f;
#pragma unroll
            for (int jj = 0; jj < 8; ++jj)
                f[jj] = (short)f2bf(bf2f((unsigned short)a[jj]) * inv);
            afr[kk] = f;
        }
        afr[2] = *(const s8bf*)&h[(size_t)r * 64 + l4 * 8];        // h half, direct bf16
        afr[3] = *(const s8bf*)&h[(size_t)r * 64 + 32 + l4 * 8];
#pragma unroll
        for (int ct = 0; ct < 4; ++ct) {
            fx4 c = {0.f, 0.f, 0.f, 0.f};
            c = __builtin_amdgcn_mfma_f32_16x16x32_bf16(afr[0], bfr[ct * 4 + 0], c, 0, 0, 0);
            c = __builtin_amdgcn_mfma_f32_16x16x32_bf16(afr[1], bfr[ct * 4 + 1], c, 0, 0, 0);
            c = __builtin_amdgcn_mfma_f32_16x16x32_bf16(afr[2], bfr[ct * 4 + 2], c, 0, 0, 0);
            c = __builtin_amdgcn_mfma_f32_16x16x32_bf16(afr[3], bfr[ct * 4 + 3], c, 0, 0, 0);
#pragma unroll
            for (int i2 = 0; i2 < 4; ++i2) {
                int row = t * 16 + l4 * 4 + i2;
                if (row < n) {
                    float o = c[i2];
                    h[(size_t)row * 64 + ct * 16 + l15] =
                        f2bf(o > 0.f ? o : __expf(o) - 1.f);
                }
            }
        }
    }
}

// ============================ tail ============================
__global__ __launch_bounds__(256) void k_gather_feat(const unsigned short* __restrict__ h,
                                                     const int* __restrict__ idx,
                                                     float* __restrict__ feat, int B,
                                                     int colOff, int FW) {
    int i = blockIdx.x * blockDim.x + threadIdx.x;
    if (i >= B * D) return;
    int b = i >> 6, c = i & 63;
    feat[(size_t)b * FW + colOff + c] = bf2f(h[(size_t)idx[b] * D + c]);
}

__global__ __launch_bounds__(64) void k_final(const float* __restrict__ feat,
                                              const float* __restrict__ uW,
                                              const float* __restrict__ dW,
                                              const float* __restrict__ db,
                                              float* __restrict__ out, int B, int FW) {
    __shared__ float fr[512];
    __shared__ float un[D];
    int b = blockIdx.x;
    int c = threadIdx.x;
    for (int i = c; i < FW; i += 64) fr[i] = feat[(size_t)b * FW + i];
    __syncthreads();
    float acc = 0.f;
    for (int d = 0; d < FW; ++d) acc += fr[d] * uW[d * D + c];
    un[c] = acc;
    __syncthreads();
    if (c < 3) {
        float o = db[c];
#pragma unroll
        for (int d = 0; d < D; ++d) o += un[d] * dW[d * 3 + c];
        out[b * 3 + c] = o > 0.f ? o : 0.f;
    }
}

// ============================ launch ============================
extern "C" void kernel_launch(void* const* d_in, const int* in_sizes, int n_in,
                              void* d_out, int out_size, void* d_ws, size_t ws_size,
                              hipStream_t stream) {
    const float* user_emb = (const float*)d_in[0];
    const float* item_emb = (const float*)d_in[1];
    const float* Wu       = (const float*)d_in[2];
    const float* Wi       = (const float*)d_in[3];
    const float* Wuu      = (const float*)d_in[4];
    const float* Wii      = (const float*)d_in[5];
    const float* u_freq   = (const float*)d_in[6];
    const float* u_phase  = (const float*)d_in[7];
    const float* uk_freq  = (const float*)d_in[8];
    const float* uk_phase = (const float*)d_in[9];
    const float* i_freq   = (const float*)d_in[10];
    const float* i_phase  = (const float*)d_in[11];
    const float* ik_freq  = (const float*)d_in[12];
    const float* ik_phase = (const float*)d_in[13];
    const float* unified_W = (const float*)d_in[14];
    const float* dense_W   = (const float*)d_in[15];
    const float* dense_b   = (const float*)d_in[16];
    const float* by_time   = (const float*)d_in[17];
    const float* pby_time  = (const float*)d_in[18];
    const int* user_id   = (const int*)d_in[19];
    const int* item_id   = (const int*)d_in[20];
    const int* by_src    = (const int*)d_in[21];
    const int* by_dst    = (const int*)d_in[22];
    const int* pby_src   = (const int*)d_in[23];
    const int* pby_dst   = (const int*)d_in[24];
    const int* user_index = (const int*)d_in[25];
    const int* last_item_index = (const int*)d_in[26];

    const int NU = in_sizes[19];
    const int NI = in_sizes[20];
    const int E  = in_sizes[21];
    const int B  = in_sizes[25];
    const int L  = in_sizes[2] / (D * D);
    const int FW = (L + 1) * D;
    const int npbU = (NU + NB - 1) / NB;
    const int npbI = (NI + NB - 1) / NB;
    const int nwgE = (E + CHUNKE - 1) / CHUNKE;

    // ---- workspace ----
    char* wp = (char*)d_ws;
    auto alloc_f = [&](size_t n) { float* p = (float*)wp; wp += n * sizeof(float); return p; };
    auto alloc_i = [&](size_t n) { int* p = (int*)wp; wp += n * sizeof(int); return p; };
    auto alloc_i4 = [&](size_t n) { ix4* p = (ix4*)wp; wp += n * sizeof(ix4); return p; };
    auto alloc_h = [&](size_t n) { unsigned short* p = (unsigned short*)wp; wp += n * sizeof(unsigned short); return p; };
    unsigned short* agg_u = alloc_h((size_t)NU * D);   // bf16 agg
    unsigned short* agg_i = alloc_h((size_t)NI * D);
    float* den_u = alloc_f(NU);
    float* den_i = alloc_f(NI);
    size_t zero_bytes = (size_t)(wp - (char*)d_ws);
    ix4* by_e    = alloc_i4(E);   // 16B-aligned: preceding sizes are multiples of 16
    ix4* pby_e   = alloc_i4(E);
    ix4* stg_by  = alloc_i4(E);
    ix4* stg_pby = alloc_i4(E);
    int* cur_u = alloc_i(NU);
    int* cur_i = alloc_i(NI);
    size_t cur_bytes = (size_t)NU * 4 + (size_t)NI * 4;
    unsigned short* user_h = alloc_h((size_t)NU * D);
    unsigned short* item_h = alloc_h((size_t)NI * D);
    unsigned short* uh = alloc_h((size_t)NU * D);
    unsigned short* ih = alloc_h((size_t)NI * D);
    unsigned short* WuT  = alloc_h((size_t)L * 64 * 64);
    unsigned short* WiT  = alloc_h((size_t)L * 64 * 64);
    unsigned short* WuuT = alloc_h((size_t)L * 64 * 128);
    unsigned short* WiiT = alloc_h((size_t)L * 64 * 128);
    int*   by_rowptr  = alloc_i(NU + 2);
    int*   pby_rowptr = alloc_i(NI + 2);
    int*   bsums      = alloc_i(512);
    int*   H          = alloc_i((size_t)2 * NB * nwgE);
    int*   gbsums     = alloc_i(512);
    float* feat       = alloc_f((size_t)B * FW);

    const int nbU = (NU + 2047) / 2048, nbI = (NI + 2047) / 2048;

    // initial node features + weight prep
    k_gather2<<<((NU + NI) * D + 255) / 256, 256, 0, stream>>>(
        user_emb, item_emb, user_id, item_id, user_h, item_h, NU, NI);
    k_wprep<<<(L * 64 * 128 + 255) / 256, 256, 0, stream>>>(Wu, Wi, Wuu, Wii,
                                                            WuT, WiT, WuuT, WiiT, L);

    // fused bucket+node histograms, then scans, partition, exact placement
    hipMemsetAsync(cur_u, 0, cur_bytes, stream);
    k_phist<<<2 * nwgE, 256, 0, stream>>>(by_dst, pby_dst, H, cur_u, cur_i, E, nwgE,
                                          (unsigned)npbU, (unsigned)npbI);
    k_scan_block2<<<nbU + nbI, 256, 0, stream>>>(cur_u, by_rowptr, cur_i, pby_rowptr,
                                                 bsums, nbU, NU, NI);
    k_scan_small<<<1, 256, 0, stream>>>(bsums, nbU, nbI);
    k_fixup2<<<(NU + NI + 255) / 256, 256, 0, stream>>>(by_rowptr, pby_rowptr, bsums,
                                                        cur_u, cur_i, NU, NI, E, nbU);
    {
        int n2 = 2 * NB * nwgE;
        int gb = (n2 + 2047) / 2048;
        k_gscan_block<<<gb, 256, 0, stream>>>(H, H, gbsums, n2);
        k_gscan_small<<<1, 256, 0, stream>>>(gbsums, gb);
        k_gscan_fix<<<(n2 + 255) / 256, 256, 0, stream>>>(H, gbsums, n2);
    }
    k_ppart<<<2 * nwgE, 256, 0, stream>>>(by_src, by_dst, by_time,
                                          pby_src, pby_dst, pby_time,
                                          H, stg_by, stg_pby, E, nwgE,
                                          (unsigned)npbU, (unsigned)npbI);
    k_sortfin<<<2 * NB, 256, 0, stream>>>(stg_by, stg_pby, by_rowptr, pby_rowptr,
                                          cur_u, cur_i, by_e, pby_e,
                                          NU, NI, npbU, npbI);

    const int EB = (E + 255) / 256;
    const int GM = 512;  // MFMA kernel blocks per table
    for (int l = 0; l < L; ++l) {
        hipMemsetAsync(d_ws, 0, zero_bytes, stream);
        k_transform4<<<2 * GM, 256, 0, stream>>>(user_h, item_h,
                                                 WuT + (size_t)l * 4096, WiT + (size_t)l * 4096,
                                                 uh, ih, NU, NI, GM);
        k_edge2<<<2 * EB, 256, 0, stream>>>(
            ih, uh, by_e, pby_e,
            u_freq + l * D, u_phase + l * D, uk_freq + l * D, uk_phase + l * D,
            i_freq + l * D, i_phase + l * D, ik_freq + l * D, ik_phase + l * D,
            agg_u, den_u, agg_i, den_i, E, EB);
        k_update4<<<2 * GM, 256, 0, stream>>>(user_h, item_h,
                                              agg_u, den_u, agg_i, den_i,
                                              WuuT + (size_t)l * 8192, WiiT + (size_t)l * 8192,
                                              NU, NI, GM);
        k_gather_feat<<<(B * D + 255) / 256, 256, 0, stream>>>(user_h, user_index, feat, B,
                                                               l * D, FW);
    }
    k_gather_feat<<<(B * D + 255) / 256, 256, 0, stream>>>(item_h, last_item_index, feat, B,
                                                           L * D, FW);
    k_final<<<B, 64, 0, stream>>>(feat, unified_W, dense_W, dense_b, (float*)d_out, B, FW);
}

// Round 17
// 611.476 us; speedup vs baseline: 1.0174x; 1.0174x over previous
//
#include <hip/hip_runtime.h>
#include <math.h>

#define D 64
#define NB 1024      // sort buckets per relation
#define CHUNKE 4096  // edges per partition workgroup

typedef __attribute__((ext_vector_type(8))) short s8bf;   // 8 x bf16 (4 VGPR) MFMA A/B frag
typedef __attribute__((ext_vector_type(4))) float fx4;    // 4 x f32 MFMA C/D frag
typedef __attribute__((ext_vector_type(4))) int ix4;      // native int4

__device__ __forceinline__ float bf2f(unsigned short u) {
    union { unsigned int i; float f; } v; v.i = ((unsigned int)u) << 16; return v.f;
}
__device__ __forceinline__ float lo2f(unsigned int u) {   // low bf16 of dword -> f32 (1 shift)
    union { unsigned int i; float f; } v; v.i = u << 16; return v.f;
}
__device__ __forceinline__ float hi2f(unsigned int u) {   // high bf16 of dword -> f32 (1 and)
    union { unsigned int i; float f; } v; v.i = u & 0xffff0000u; return v.f;
}
__device__ __forceinline__ unsigned short f2bf(float f) {
    union { float f; unsigned int i; } v; v.f = f;
    unsigned int r = v.i + 0x7FFFu + ((v.i >> 16) & 1u);
    return (unsigned short)(r >> 16);
}
// hardware packed bf16 atomic add (gfx942+/gfx950); inline asm avoids header dependence
__device__ __forceinline__ void atomAddPkBf16(unsigned short* addr, float a, float b) {
    unsigned int pk = ((unsigned int)f2bf(b) << 16) | (unsigned int)f2bf(a);
    asm volatile("global_atomic_pk_add_bf16 %0, %1, off" :: "v"(addr), "v"(pk) : "memory");
}

// ============================ initial gather (both tables -> bf16, one launch) ====================
__global__ __launch_bounds__(256) void k_gather2(const float* __restrict__ ue,
                                                 const float* __restrict__ ie,
                                                 const int* __restrict__ uid,
                                                 const int* __restrict__ iid,
                                                 unsigned short* __restrict__ uh0,
                                                 unsigned short* __restrict__ ih0, int NU, int NI) {
    int i = blockIdx.x * blockDim.x + threadIdx.x;
    if (i >= (NU + NI) * D) return;
    int r = i >> 6, c = i & 63;
    if (r < NU) uh0[(size_t)r * D + c] = f2bf(ue[(size_t)uid[r] * D + c]);
    else { int j = r - NU; ih0[(size_t)j * D + c] = f2bf(ie[(size_t)iid[j] * D + c]); }
}

// ============================ weight transpose+bf16 prep (once) ============================
__global__ __launch_bounds__(256) void k_wprep(const float* __restrict__ Wu,
                                               const float* __restrict__ Wi,
                                               const float* __restrict__ Wuu,
                                               const float* __restrict__ Wii,
                                               unsigned short* __restrict__ WuT,
                                               unsigned short* __restrict__ WiT,
                                               unsigned short* __restrict__ WuuT,
                                               unsigned short* __restrict__ WiiT, int L) {
    int i = blockIdx.x * blockDim.x + threadIdx.x;
    int n1 = L * 64 * 64, n2 = L * 64 * 128;
    if (i < n1) {
        int l = i >> 12, c = (i >> 6) & 63, k = i & 63;
        WuT[i] = f2bf(Wu[l * 4096 + k * 64 + c]);
        WiT[i] = f2bf(Wi[l * 4096 + k * 64 + c]);
    }
    if (i < n2) {
        int l = i >> 13, c = (i >> 7) & 63, k = i & 127;
        WuuT[i] = f2bf(Wuu[l * 8192 + k * 64 + c]);
        WiiT[i] = f2bf(Wii[l * 8192 + k * 64 + c]);
    }
}

// ============================ node-level CSR scan kernels ============================
__global__ __launch_bounds__(256) void k_scan_block2(const int* __restrict__ cu, int* __restrict__ rp_u,
                                                     const int* __restrict__ ci, int* __restrict__ rp_i,
                                                     int* __restrict__ bsums, int nbU, int NU, int NI) {
    __shared__ int ts[256];
    bool rel = blockIdx.x >= (unsigned)nbU;
    const int* in = rel ? ci : cu;
    int* out = rel ? rp_i : rp_u;
    int n = rel ? NI : NU;
    int boff = rel ? blockIdx.x - nbU : blockIdx.x;
    int t = threadIdx.x;
    int base = boff * 2048 + t * 8;
    int v[8]; int s = 0;
#pragma unroll
    for (int k = 0; k < 8; ++k) { int idx = base + k; v[k] = idx < n ? in[idx] : 0; s += v[k]; }
    ts[t] = s; __syncthreads();
    for (int off = 1; off < 256; off <<= 1) {
        int x = (t >= off) ? ts[t - off] : 0;
        __syncthreads(); ts[t] += x; __syncthreads();
    }
    int excl = ts[t] - s;
    if (t == 255) bsums[blockIdx.x] = ts[255];
    int run = excl;
#pragma unroll
    for (int k = 0; k < 8; ++k) { int idx = base + k; if (idx < n) out[idx] = run; run += v[k]; }
}

__global__ __launch_bounds__(256) void k_scan_small(int* __restrict__ bsums, int nbU, int nbI) {
    __shared__ int ts[256];
    int t = threadIdx.x;
    int half = t >> 7, local = t & 127;
    int nb = half ? nbI : nbU;
    int g = half ? nbU + local : local;
    int v = local < nb ? bsums[g] : 0;
    ts[t] = v; __syncthreads();
    for (int off = 1; off < 128; off <<= 1) {
        int x = (local >= off) ? ts[t - off] : 0;
        __syncthreads(); ts[t] += x; __syncthreads();
    }
    if (local < nb) bsums[g] = ts[t] - v;
}

__global__ __launch_bounds__(256) void k_fixup2(int* __restrict__ rp_u, int* __restrict__ rp_i,
                                                const int* __restrict__ bsums,
                                                int* __restrict__ cu, int* __restrict__ ci,
                                                int NU, int NI, int E, int nbU) {
    int i = blockIdx.x * blockDim.x + threadIdx.x;
    if (i < NU) {
        int v = rp_u[i] + bsums[i >> 11]; rp_u[i] = v; cu[i] = v;
        if (i == 0) rp_u[NU] = E;
    } else if (i < NU + NI) {
        int j = i - NU;
        int v = rp_i[j] + bsums[nbU + (j >> 11)]; rp_i[j] = v; ci[j] = v;
        if (j == 0) rp_i[NI] = E;
    }
}

// ============================ radix partition pass 1: bucket hist + node hist (fused) ============
__global__ __launch_bounds__(256) void k_phist(const int* __restrict__ bd,
                                               const int* __restrict__ pd,
                                               int* __restrict__ H,
                                               int* __restrict__ cu, int* __restrict__ ci,
                                               int E, int nwgE,
                                               unsigned npbU, unsigned npbI) {
    bool rel = blockIdx.x >= (unsigned)nwgE;
    int wg = rel ? blockIdx.x - nwgE : blockIdx.x;
    const int* dsts = rel ? pd : bd;
    unsigned npb = rel ? npbI : npbU;
    int* Hr = H + (rel ? NB * nwgE : 0);
    int* nodecnt = rel ? ci : cu;
    __shared__ int hist[NB];
    int t = threadIdx.x;
    for (int j = t; j < NB; j += 256) hist[j] = 0;
    __syncthreads();
    int base = wg * CHUNKE;
#pragma unroll
    for (int k = 0; k < CHUNKE / 256; ++k) {
        int e = base + t + k * 256;
        if (e < E) {
            int d = dsts[e];
            atomicAdd(&hist[(unsigned)d / npb], 1);
            atomicAdd(&nodecnt[d], 1);
        }
    }
    __syncthreads();
    for (int j = t; j < NB; j += 256) Hr[j * nwgE + wg] = hist[j];
}

// generic exclusive scan (3 kernels) over H
__global__ __launch_bounds__(256) void k_gscan_block(const int* __restrict__ in,
                                                     int* __restrict__ out,
                                                     int* __restrict__ bsums, int n) {
    __shared__ int ts[256];
    int t = threadIdx.x;
    int base = blockIdx.x * 2048 + t * 8;
    int v[8]; int s = 0;
#pragma unroll
    for (int k = 0; k < 8; ++k) { int idx = base + k; v[k] = idx < n ? in[idx] : 0; s += v[k]; }
    ts[t] = s; __syncthreads();
    for (int off = 1; off < 256; off <<= 1) {
        int x = (t >= off) ? ts[t - off] : 0;
        __syncthreads(); ts[t] += x; __syncthreads();
    }
    int excl = ts[t] - s;
    if (t == 255) bsums[blockIdx.x] = ts[255];
    int run = excl;
#pragma unroll
    for (int k = 0; k < 8; ++k) { int idx = base + k; if (idx < n) out[idx] = run; run += v[k]; }
}

__global__ __launch_bounds__(256) void k_gscan_small(int* __restrict__ bsums, int nb) {
    __shared__ int ts[256];
    int t = threadIdx.x;
    int v = t < nb ? bsums[t] : 0;
    ts[t] = v; __syncthreads();
    for (int off = 1; off < 256; off <<= 1) {
        int x = (t >= off) ? ts[t - off] : 0;
        __syncthreads(); ts[t] += x; __syncthreads();
    }
    if (t < nb) bsums[t] = ts[t] - v;
}

__global__ __launch_bounds__(256) void k_gscan_fix(int* __restrict__ out,
                                                   const int* __restrict__ bsums, int n) {
    int i = blockIdx.x * blockDim.x + threadIdx.x;
    if (i < n) out[i] += bsums[i >> 11];
}

// ============================ radix partition pass 2: place via LDS cursors ======================
__global__ __launch_bounds__(256) void k_ppart(
    const int* __restrict__ bs, const int* __restrict__ bd, const float* __restrict__ bt,
    const int* __restrict__ ps, const int* __restrict__ pd, const float* __restrict__ pt,
    const int* __restrict__ H, ix4* __restrict__ stg_by, ix4* __restrict__ stg_pby,
    int E, int nwgE, unsigned npbU, unsigned npbI) {
    bool rel = blockIdx.x >= (unsigned)nwgE;
    int wg = rel ? blockIdx.x - nwgE : blockIdx.x;
    const int* srcs = rel ? ps : bs;
    const int* dsts = rel ? pd : bd;
    const float* tms = rel ? pt : bt;
    unsigned npb = rel ? npbI : npbU;
    const int* Hr = H + (rel ? NB * nwgE : 0);
    ix4* stg = rel ? stg_pby : stg_by;
    int sub = rel ? E : 0;
    __shared__ int cur[NB];
    int t = threadIdx.x;
    for (int j = t; j < NB; j += 256) cur[j] = Hr[j * nwgE + wg] - sub;
    __syncthreads();
    int base = wg * CHUNKE;
#pragma unroll
    for (int k = 0; k < CHUNKE / 256; ++k) {
        int e = base + t + k * 256;
        if (e < E) {
            int d = dsts[e];
            int pos = atomicAdd(&cur[(unsigned)d / npb], 1);
            ix4 v = {srcs[e], __float_as_int(tms[e]), d, 0};
            stg[pos] = v;
        }
    }
}

// pass 3: one WG per bucket; exact per-node placement (bucket window L2-resident)
__global__ __launch_bounds__(256) void k_sortfin(
    const ix4* __restrict__ stg_by, const ix4* __restrict__ stg_pby,
    const int* __restrict__ rp_u, const int* __restrict__ rp_i,
    int* __restrict__ cu, int* __restrict__ ci,
    ix4* __restrict__ by_e, ix4* __restrict__ pby_e,
    int NU, int NI, int npbU, int npbI) {
    bool rel = blockIdx.x >= (unsigned)NB;
    int b = rel ? blockIdx.x - NB : blockIdx.x;
    const ix4* stg = rel ? stg_pby : stg_by;
    const int* rp = rel ? rp_i : rp_u;
    int* cur = rel ? ci : cu;
    ix4* out = rel ? pby_e : by_e;
    int n = rel ? NI : NU;
    int npb = rel ? npbI : npbU;
    long long s0 = (long long)b * npb; if (s0 > n) s0 = n;
    long long s1 = (long long)(b + 1) * npb; if (s1 > n) s1 = n;
    int beg = rp[s0], end = rp[s1];
    for (int j = beg + threadIdx.x; j < end; j += 256) {
        ix4 q = stg[j];
        int pos = atomicAdd(&cur[q.z], 1);
        out[pos] = q;
    }
}

// ============================ transform: MFMA 16x16x32 bf16 (h is bf16) ==========================
__global__ __launch_bounds__(256) void k_transform4(
    const unsigned short* __restrict__ user_h, const unsigned short* __restrict__ item_h,
    const unsigned short* __restrict__ WuT_l, const unsigned short* __restrict__ WiT_l,
    unsigned short* __restrict__ uh, unsigned short* __restrict__ ih,
    int NU, int NI, int G) {
    bool rel = blockIdx.x >= (unsigned)G;
    int b = rel ? blockIdx.x - G : blockIdx.x;
    const unsigned short* in = rel ? item_h : user_h;
    const unsigned short* WT = rel ? WiT_l : WuT_l;
    unsigned short* out = rel ? ih : uh;
    int n = rel ? NI : NU;
    int lane = threadIdx.x & 63;
    int l15 = lane & 15, l4 = lane >> 4;
    s8bf bfr[8];
#pragma unroll
    for (int ct = 0; ct < 4; ++ct)
#pragma unroll
        for (int kk = 0; kk < 2; ++kk)
            bfr[ct * 2 + kk] = *(const s8bf*)&WT[(ct * 16 + l15) * 64 + kk * 32 + l4 * 8];
    int wave = b * 4 + (threadIdx.x >> 6);
    int nw = G * 4;
    int ntiles = (n + 15) >> 4;
    for (int t = wave; t < ntiles; t += nw) {
        int r = t * 16 + l15; if (r >= n) r = n - 1;
        s8bf afr0 = *(const s8bf*)&in[(size_t)r * 64 + l4 * 8];
        s8bf afr1 = *(const s8bf*)&in[(size_t)r * 64 + 32 + l4 * 8];
#pragma unroll
        for (int ct = 0; ct < 4; ++ct) {
            fx4 c = {0.f, 0.f, 0.f, 0.f};
            c = __builtin_amdgcn_mfma_f32_16x16x32_bf16(afr0, bfr[ct * 2 + 0], c, 0, 0, 0);
            c = __builtin_amdgcn_mfma_f32_16x16x32_bf16(afr1, bfr[ct * 2 + 1], c, 0, 0, 0);
#pragma unroll
            for (int i2 = 0; i2 < 4; ++i2) {
                int row = t * 16 + l4 * 4 + i2;
                if (row < n) out[(size_t)row * 64 + ct * 16 + l15] = f2bf(c[i2]);
            }
        }
    }
}

// ============================ edge kernel: 16-lane groups, 32-bit addressing ======================
// VALU cuts vs round-16 (diagnosed from 164-inst/iter measurement): 32-bit byte-offset
// addressing for row loads (SGPR base + voffset, no 64-bit addr chains); high-bf16
// extract via single mask; hoisted loop bound.
__global__ __launch_bounds__(256) void k_edge2(
    const unsigned short* __restrict__ ihF, const unsigned short* __restrict__ uhF,
    const ix4* __restrict__ by_e, const ix4* __restrict__ pby_e,
    const float* __restrict__ uf, const float* __restrict__ up,
    const float* __restrict__ ukf, const float* __restrict__ ukp,
    const float* __restrict__ ifq, const float* __restrict__ ipq,
    const float* __restrict__ ikf, const float* __restrict__ ikp,
    unsigned short* __restrict__ agg_u, float* __restrict__ den_u,
    unsigned short* __restrict__ agg_i, float* __restrict__ den_i,
    int E, int EB) {
    bool rel = blockIdx.x >= (unsigned)EB;  // false: 'by' item->user, true: 'pby' user->item
    int rblk = rel ? blockIdx.x - EB : blockIdx.x;
    const char* srcB = (const char*)(rel ? uhF : ihF);
    const char* dstB = (const char*)(rel ? ihF : uhF);
    const ix4* ee = rel ? pby_e : by_e;
    const float* efq = rel ? ifq : uf;
    const float* eps = rel ? ipq : up;
    const float* kfq = rel ? ikf : ukf;
    const float* kps = rel ? ikp : ukp;
    unsigned short* agg = rel ? agg_i : agg_u;
    float* den = rel ? den_i : den_u;

    int lane = threadIdx.x & 15;
    int grp  = threadIdx.x >> 4;
    int base = rblk * 256 + grp * 16;
    if (base >= E) return;
    int nedge = E - base; if (nedge > 16) nedge = 16;
    unsigned loff = (unsigned)(lane * 4);   // byte offset of this lane's dword within a row
    float2 ef01 = ((const float2*)efq)[lane];        // dims 2l, 2l+1
    float2 ef23 = ((const float2*)efq)[lane + 16];   // dims 32+2l, 32+2l+1
    float2 ep01 = ((const float2*)eps)[lane];
    float2 ep23 = ((const float2*)eps)[lane + 16];
    float2 kf01 = ((const float2*)kfq)[lane];
    float2 kf23 = ((const float2*)kfq)[lane + 16];
    float2 kp01 = ((const float2*)kps)[lane];
    float2 kp23 = ((const float2*)kps)[lane + 16];
    bool same = ef01.x == kf01.x && ef01.y == kf01.y && ef23.x == kf23.x && ef23.y == kf23.y &&
                ep01.x == kp01.x && ep01.y == kp01.y && ep23.x == kp23.x && ep23.y == kp23.y;
    same = __all(same);  // uniform: key time-encode identical to e time-encode (raw compare)
    const float R = 0.15915494309189535f;  // rad -> revolutions for raw v_cos
    ef01.x *= R; ef01.y *= R; ef23.x *= R; ef23.y *= R;
    ep01.x *= R; ep01.y *= R; ep23.x *= R; ep23.y *= R;
    kf01.x *= R; kf01.y *= R; kf23.x *= R; kf23.y *= R;
    kp01.x *= R; kp01.y *= R; kp23.x *= R; kp23.y *= R;

    float a0 = 0, a1 = 0, a2 = 0, a3 = 0, dn = 0;
    float d0 = 0, d1 = 0, d2 = 0, d3 = 0;
    int cur = -1;
    for (int j = 0; j < nedge; ++j) {
        ix4 q = ee[base + j];                   // broadcast 16B
        int s = q.x; float t = __int_as_float(q.y); int dd = q.z;
        if (dd != cur) {  // group-uniform
            if (cur >= 0) {
                unsigned short* ap = &agg[(size_t)cur * D + 2 * lane];
                atomAddPkBf16(ap, a0, a1);
                atomAddPkBf16(ap + 32, a2, a3);
                if (lane == 0) unsafeAtomicAdd(&den[cur], dn);
            }
            a0 = a1 = a2 = a3 = 0; dn = 0; cur = dd;
            unsigned doffb = (unsigned)dd * 128u + loff;
            unsigned int u0 = *(const unsigned int*)(dstB + doffb);
            unsigned int u1 = *(const unsigned int*)(dstB + doffb + 64u);
            d0 = lo2f(u0); d1 = hi2f(u0); d2 = lo2f(u1); d3 = hi2f(u1);
        }
        unsigned soffb = (unsigned)s * 128u + loff;
        unsigned int s01 = *(const unsigned int*)(srcB + soffb);
        unsigned int s23 = *(const unsigned int*)(srcB + soffb + 64u);
        float s0 = lo2f(s01), s1 = hi2f(s01);
        float s2 = lo2f(s23), s3 = hi2f(s23);
        float c0 = __builtin_amdgcn_cosf(fmaf(t, ef01.x, ep01.x));
        float c1 = __builtin_amdgcn_cosf(fmaf(t, ef01.y, ep01.y));
        float c2 = __builtin_amdgcn_cosf(fmaf(t, ef23.x, ep23.x));
        float c3 = __builtin_amdgcn_cosf(fmaf(t, ef23.y, ep23.y));
        float t0 = c0 + s0, t1 = c1 + s1, t2 = c2 + s2, t3 = c3 + s3;
        float p = t0 * d0 + t1 * d1 + t2 * d2 + t3 * d3;
        p += __shfl_xor(p, 1); p += __shfl_xor(p, 2);
        p += __shfl_xor(p, 4); p += __shfl_xor(p, 8);
        float ex = __expf(p * 0.125f);
        if (same) {  // s + k == s + c == t (dot terms reused)
            a0 = fmaf(ex, t0, a0); a1 = fmaf(ex, t1, a1);
            a2 = fmaf(ex, t2, a2); a3 = fmaf(ex, t3, a3);
        } else {
            float k0 = __builtin_amdgcn_cosf(fmaf(t, kf01.x, kp01.x));
            float k1 = __builtin_amdgcn_cosf(fmaf(t, kf01.y, kp01.y));
            float k2 = __builtin_amdgcn_cosf(fmaf(t, kf23.x, kp23.x));
            float k3 = __builtin_amdgcn_cosf(fmaf(t, kf23.y, kp23.y));
            a0 = fmaf(ex, s0 + k0, a0); a1 = fmaf(ex, s1 + k1, a1);
            a2 = fmaf(ex, s2 + k2, a2); a3 = fmaf(ex, s3 + k3, a3);
        }
        dn += ex;
    }
    if (cur >= 0) {
        unsigned short* ap = &agg[(size_t)cur * D + 2 * lane];
        atomAddPkBf16(ap, a0, a1);
        atomAddPkBf16(ap + 32, a2, a3);
        if (lane == 0) unsafeAtomicAdd(&den[cur], dn);
    }
}

// ============================ update: MFMA 16x16x32 bf16, K=128, in-place ELU (agg+h bf16) =======
__global__ __launch_bounds__(256) void k_update4(
    unsigned short* __restrict__ user_h, unsigned short* __restrict__ item_h,
    const unsigned short* __restrict__ agg_u, const float* __restrict__ den_u,
    const unsigned short* __restrict__ agg_i, const float* __restrict__ den_i,
    const unsigned short* __restrict__ WuuT_l, const unsigned short* __restrict__ WiiT_l,
    int NU, int NI, int G) {
    bool rel = blockIdx.x >= (unsigned)G;
    int b = rel ? blockIdx.x - G : blockIdx.x;
    unsigned short* h = rel ? item_h : user_h;
    const unsigned short* agg = rel ? agg_i : agg_u;
    const float* den = rel ? den_i : den_u;
    const unsigned short* WT = rel ? WiiT_l : WuuT_l;
    int n = rel ? NI : NU;
    int lane = threadIdx.x & 63;
    int l15 = lane & 15, l4 = lane >> 4;
    s8bf bfr[16];
#pragma unroll
    for (int ct = 0; ct < 4; ++ct)
#pragma unroll
        for (int kk = 0; kk < 4; ++kk)
            bfr[ct * 4 + kk] = *(const s8bf*)&WT[(ct * 16 + l15) * 128 + kk * 32 + l4 * 8];
    int wave = b * 4 + (threadIdx.x >> 6);
    int nw = G * 4;
    int ntiles = (n + 15) >> 4;
    for (int t = wave; t < ntiles; t += nw) {
        int r = t * 16 + l15; if (r >= n) r = n - 1;
        float dd = den[r];
        float inv = dd > 0.f ? 1.f / dd : 0.f;   // empty segment -> agg contribution 0
        s8bf afr[4];
#pragma unroll
        for (int kk = 0; kk < 2; ++kk) {         // agg half (bf16), scale by inv
            s8bf a = *(const s8bf*)&agg[(size_t)r * 64 + kk * 32 + l4 * 8];
            s8bf f;
#pragma unroll
            for (int jj = 0; jj < 8; ++jj)
                f[jj] = (short)f2bf(bf2f((unsigned short)a[jj]) * inv);
            afr[kk] = f;
        }
        afr[2] = *(const s8bf*)&h[(size_t)r * 64 + l4 * 8];        // h half, direct bf16
        afr[3] = *(const s8bf*)&h[(size_t)r * 64 + 32 + l4 * 8];
#pragma unroll
        for (int ct = 0; ct < 4; ++ct) {
            fx4 c = {0.f, 0.f, 0.f, 0.f};
            c = __builtin_amdgcn_mfma_f32_16x16x32_bf16(afr[0], bfr[ct * 4 + 0], c, 0, 0, 0);
            c = __builtin_amdgcn_mfma_f32_16x16x32_bf16(afr[1], bfr[ct * 4 + 1], c, 0, 0, 0);
            c = __builtin_amdgcn_mfma_f32_16x16x32_bf16(afr[2], bfr[ct * 4 + 2], c, 0, 0, 0);
            c = __builtin_amdgcn_mfma_f32_16x16x32_bf16(afr[3], bfr[ct * 4 + 3], c, 0, 0, 0);
#pragma unroll
            for (int i2 = 0; i2 < 4; ++i2) {
                int row = t * 16 + l4 * 4 + i2;
                if (row < n) {
                    float o = c[i2];
                    h[(size_t)row * 64 + ct * 16 + l15] =
                        f2bf(o > 0.f ? o : __expf(o) - 1.f);
                }
            }
        }
    }
}

// ============================ tail ============================
__global__ __launch_bounds__(256) void k_gather_feat(const unsigned short* __restrict__ h,
                                                     const int* __restrict__ idx,
                                                     float* __restrict__ feat, int B,
                                                     int colOff, int FW) {
    int i = blockIdx.x * blockDim.x + threadIdx.x;
    if (i >= B * D) return;
    int b = i >> 6, c = i & 63;
    feat[(size_t)b * FW + colOff + c] = bf2f(h[(size_t)idx[b] * D + c]);
}

__global__ __launch_bounds__(64) void k_final(const float* __restrict__ feat,
                                              const float* __restrict__ uW,
                                              const float* __restrict__ dW,
                                              const float* __restrict__ db,
                                              float* __restrict__ out, int B, int FW) {
    __shared__ float fr[512];
    __shared__ float un[D];
    int b = blockIdx.x;
    int c = threadIdx.x;
    for (int i = c; i < FW; i += 64) fr[i] = feat[(size_t)b * FW + i];
    __syncthreads();
    float acc = 0.f;
    for (int d = 0; d < FW; ++d) acc += fr[d] * uW[d * D + c];
    un[c] = acc;
    __syncthreads();
    if (c < 3) {
        float o = db[c];
#pragma unroll
        for (int d = 0; d < D; ++d) o += un[d] * dW[d * 3 + c];
        out[b * 3 + c] = o > 0.f ? o : 0.f;
    }
}

// ============================ launch ============================
extern "C" void kernel_launch(void* const* d_in, const int* in_sizes, int n_in,
                              void* d_out, int out_size, void* d_ws, size_t ws_size,
                              hipStream_t stream) {
    const float* user_emb = (const float*)d_in[0];
    const float* item_emb = (const float*)d_in[1];
    const float* Wu       = (const float*)d_in[2];
    const float* Wi       = (const float*)d_in[3];
    const float* Wuu      = (const float*)d_in[4];
    const float* Wii      = (const float*)d_in[5];
    const float* u_freq   = (const float*)d_in[6];
    const float* u_phase  = (const float*)d_in[7];
    const float* uk_freq  = (const float*)d_in[8];
    const float* uk_phase = (const float*)d_in[9];
    const float* i_freq   = (const float*)d_in[10];
    const float* i_phase  = (const float*)d_in[11];
    const float* ik_freq  = (const float*)d_in[12];
    const float* ik_phase = (const float*)d_in[13];
    const float* unified_W = (const float*)d_in[14];
    const float* dense_W   = (const float*)d_in[15];
    const float* dense_b   = (const float*)d_in[16];
    const float* by_time   = (const float*)d_in[17];
    const float* pby_time  = (const float*)d_in[18];
    const int* user_id   = (const int*)d_in[19];
    const int* item_id   = (const int*)d_in[20];
    const int* by_src    = (const int*)d_in[21];
    const int* by_dst    = (const int*)d_in[22];
    const int* pby_src   = (const int*)d_in[23];
    const int* pby_dst   = (const int*)d_in[24];
    const int* user_index = (const int*)d_in[25];
    const int* last_item_index = (const int*)d_in[26];

    const int NU = in_sizes[19];
    const int NI = in_sizes[20];
    const int E  = in_sizes[21];
    const int B  = in_sizes[25];
    const int L  = in_sizes[2] / (D * D);
    const int FW = (L + 1) * D;
    const int npbU = (NU + NB - 1) / NB;
    const int npbI = (NI + NB - 1) / NB;
    const int nwgE = (E + CHUNKE - 1) / CHUNKE;

    // ---- workspace ----
    char* wp = (char*)d_ws;
    auto alloc_f = [&](size_t n) { float* p = (float*)wp; wp += n * sizeof(float); return p; };
    auto alloc_i = [&](size_t n) { int* p = (int*)wp; wp += n * sizeof(int); return p; };
    auto alloc_i4 = [&](size_t n) { ix4* p = (ix4*)wp; wp += n * sizeof(ix4); return p; };
    auto alloc_h = [&](size_t n) { unsigned short* p = (unsigned short*)wp; wp += n * sizeof(unsigned short); return p; };
    unsigned short* agg_u = alloc_h((size_t)NU * D);   // bf16 agg
    unsigned short* agg_i = alloc_h((size_t)NI * D);
    float* den_u = alloc_f(NU);
    float* den_i = alloc_f(NI);
    size_t zero_bytes = (size_t)(wp - (char*)d_ws);
    ix4* by_e    = alloc_i4(E);   // 16B-aligned: preceding sizes are multiples of 16
    ix4* pby_e   = alloc_i4(E);
    ix4* stg_by  = alloc_i4(E);
    ix4* stg_pby = alloc_i4(E);
    int* cur_u = alloc_i(NU);
    int* cur_i = alloc_i(NI);
    size_t cur_bytes = (size_t)NU * 4 + (size_t)NI * 4;
    unsigned short* user_h = alloc_h((size_t)NU * D);
    unsigned short* item_h = alloc_h((size_t)NI * D);
    unsigned short* uh = alloc_h((size_t)NU * D);
    unsigned short* ih = alloc_h((size_t)NI * D);
    unsigned short* WuT  = alloc_h((size_t)L * 64 * 64);
    unsigned short* WiT  = alloc_h((size_t)L * 64 * 64);
    unsigned short* WuuT = alloc_h((size_t)L * 64 * 128);
    unsigned short* WiiT = alloc_h((size_t)L * 64 * 128);
    int*   by_rowptr  = alloc_i(NU + 2);
    int*   pby_rowptr = alloc_i(NI + 2);
    int*   bsums      = alloc_i(512);
    int*   H          = alloc_i((size_t)2 * NB * nwgE);
    int*   gbsums     = alloc_i(512);
    float* feat       = alloc_f((size_t)B * FW);

    const int nbU = (NU + 2047) / 2048, nbI = (NI + 2047) / 2048;

    // initial node features + weight prep
    k_gather2<<<((NU + NI) * D + 255) / 256, 256, 0, stream>>>(
        user_emb, item_emb, user_id, item_id, user_h, item_h, NU, NI);
    k_wprep<<<(L * 64 * 128 + 255) / 256, 256, 0, stream>>>(Wu, Wi, Wuu, Wii,
                                                            WuT, WiT, WuuT, WiiT, L);

    // fused bucket+node histograms, then scans, partition, exact placement
    hipMemsetAsync(cur_u, 0, cur_bytes, stream);
    k_phist<<<2 * nwgE, 256, 0, stream>>>(by_dst, pby_dst, H, cur_u, cur_i, E, nwgE,
                                          (unsigned)npbU, (unsigned)npbI);
    k_scan_block2<<<nbU + nbI, 256, 0, stream>>>(cur_u, by_rowptr, cur_i, pby_rowptr,
                                                 bsums, nbU, NU, NI);
    k_scan_small<<<1, 256, 0, stream>>>(bsums, nbU, nbI);
    k_fixup2<<<(NU + NI + 255) / 256, 256, 0, stream>>>(by_rowptr, pby_rowptr, bsums,
                                                        cur_u, cur_i, NU, NI, E, nbU);
    {
        int n2 = 2 * NB * nwgE;
        int gb = (n2 + 2047) / 2048;
        k_gscan_block<<<gb, 256, 0, stream>>>(H, H, gbsums, n2);
        k_gscan_small<<<1, 256, 0, stream>>>(gbsums, gb);
        k_gscan_fix<<<(n2 + 255) / 256, 256, 0, stream>>>(H, gbsums, n2);
    }
    k_ppart<<<2 * nwgE, 256, 0, stream>>>(by_src, by_dst, by_time,
                                          pby_src, pby_dst, pby_time,
                                          H, stg_by, stg_pby, E, nwgE,
                                          (unsigned)npbU, (unsigned)npbI);
    k_sortfin<<<2 * NB, 256, 0, stream>>>(stg_by, stg_pby, by_rowptr, pby_rowptr,
                                          cur_u, cur_i, by_e, pby_e,
                                          NU, NI, npbU, npbI);

    const int EB = (E + 255) / 256;
    const int GM = 512;  // MFMA kernel blocks per table
    for (int l = 0; l < L; ++l) {
        hipMemsetAsync(d_ws, 0, zero_bytes, stream);
        k_transform4<<<2 * GM, 256, 0, stream>>>(user_h, item_h,
                                                 WuT + (size_t)l * 4096, WiT + (size_t)l * 4096,
                                                 uh, ih, NU, NI, GM);
        k_edge2<<<2 * EB, 256, 0, stream>>>(
            ih, uh, by_e, pby_e,
            u_freq + l * D, u_phase + l * D, uk_freq + l * D, uk_phase + l * D,
            i_freq + l * D, i_phase + l * D, ik_freq + l * D, ik_phase + l * D,
            agg_u, den_u, agg_i, den_i, E, EB);
        k_update4<<<2 * GM, 256, 0, stream>>>(user_h, item_h,
                                              agg_u, den_u, agg_i, den_i,
                                              WuuT + (size_t)l * 8192, WiiT + (size_t)l * 8192,
                                              NU, NI, GM);
        k_gather_feat<<<(B * D + 255) / 256, 256, 0, stream>>>(user_h, user_index, feat, B,
                                                               l * D, FW);
    }
    k_gather_feat<<<(B * D + 255) / 256, 256, 0, stream>>>(item_h, last_item_index, feat, B,
                                                           L * D, FW);
    k_final<<<B, 64, 0, stream>>>(feat, unified_W, dense_W, dense_b, (float*)d_out, B, FW);
}